// Round 1
// baseline (166.639 us; speedup 1.0000x reference)
//
#include <hip/hip_runtime.h>
#include <hip/hip_bf16.h>

#define BSAMP 8192
#define NCLS 400
#define DIM 768
#define MROWS 16384
#define LOGITS_SIZE (16384LL * 400LL)

typedef __attribute__((ext_vector_type(8))) short short8;
typedef __attribute__((ext_vector_type(4))) float floatx4;

// ---------- fp32 -> bf16 round-to-nearest-even (no NaN in this workload) ----------
__device__ inline unsigned short f2bf(float f) {
    unsigned int u = __float_as_uint(f);
    return (unsigned short)((u + 0x7FFFu + ((u >> 16) & 1u)) >> 16);
}

__device__ inline uint4 pack8(float4 a, float4 b) {
    union { unsigned short u[8]; uint4 v; } p;
    p.u[0] = f2bf(a.x); p.u[1] = f2bf(a.y); p.u[2] = f2bf(a.z); p.u[3] = f2bf(a.w);
    p.u[4] = f2bf(b.x); p.u[5] = f2bf(b.y); p.u[6] = f2bf(b.z); p.u[7] = f2bf(b.w);
    return p.v;
}

// ============================ GEMM: logits = E @ W^T + b ============================
// Block tile: 128(M) x 80(N), BK=32. 4 waves; wave w owns rows [32w,32w+32) x 80 cols.
// Per wave: 2 m-tiles x 5 n-tiles of 16x16x32 bf16 MFMA.
__global__ __launch_bounds__(256) void gemm_kernel(const float* __restrict__ E,
                                                   const float* __restrict__ W,
                                                   const float* __restrict__ bias,
                                                   float* __restrict__ out) {
    __shared__ __align__(16) unsigned short sA[128 * 32];  // [row][k]
    __shared__ __align__(16) unsigned short sB[80 * 32];   // [n][k]  (W row-major slice)

    const int t    = threadIdx.x;
    const int n0   = blockIdx.x * 80;    // 5 n-blocks
    const int m0   = blockIdx.y * 128;   // 128 m-blocks
    const int wave = t >> 6;
    const int lane = t & 63;
    const int quad = lane >> 4;
    const int l16  = lane & 15;

    // staging assignment: thread t -> (row = t/2, 16 k-elems at (t&1)*16)
    const int aRow = t >> 1;
    const int aCol = (t & 1) * 16;
    const float* aSrc = E + (size_t)(m0 + aRow) * DIM + aCol;
    const float* bSrc = W + (size_t)(n0 + aRow) * DIM + aCol;  // valid only for t<160

    floatx4 acc[2][5];
#pragma unroll
    for (int mi = 0; mi < 2; ++mi)
#pragma unroll
        for (int ni = 0; ni < 5; ++ni)
            acc[mi][ni] = (floatx4){0.f, 0.f, 0.f, 0.f};

    for (int k0 = 0; k0 < DIM; k0 += 32) {
        // ---- stage A: 128x32 fp32 -> bf16 ----
        {
            const float4* s = (const float4*)(aSrc + k0);
            float4 f0 = s[0], f1 = s[1], f2 = s[2], f3 = s[3];
            *(uint4*)&sA[aRow * 32 + aCol]     = pack8(f0, f1);
            *(uint4*)&sA[aRow * 32 + aCol + 8] = pack8(f2, f3);
        }
        // ---- stage B (W): 80x32 fp32 -> bf16 ----
        if (t < 160) {
            const float4* s = (const float4*)(bSrc + k0);
            float4 f0 = s[0], f1 = s[1], f2 = s[2], f3 = s[3];
            *(uint4*)&sB[aRow * 32 + aCol]     = pack8(f0, f1);
            *(uint4*)&sB[aRow * 32 + aCol + 8] = pack8(f2, f3);
        }
        __syncthreads();

        // ---- fragments + MFMA ----
        short8 af0 = *(const short8*)&sA[(wave * 32 + l16) * 32 + quad * 8];
        short8 af1 = *(const short8*)&sA[(wave * 32 + 16 + l16) * 32 + quad * 8];
#pragma unroll
        for (int ni = 0; ni < 5; ++ni) {
            short8 bf = *(const short8*)&sB[(ni * 16 + l16) * 32 + quad * 8];
            acc[0][ni] = __builtin_amdgcn_mfma_f32_16x16x32_bf16(af0, bf, acc[0][ni], 0, 0, 0);
            acc[1][ni] = __builtin_amdgcn_mfma_f32_16x16x32_bf16(af1, bf, acc[1][ni], 0, 0, 0);
        }
        __syncthreads();
    }

    // ---- epilogue: C/D layout col=lane&15, row=quad*4+reg ----
#pragma unroll
    for (int ni = 0; ni < 5; ++ni) {
        int col = n0 + ni * 16 + l16;
        float bv = bias[col];
#pragma unroll
        for (int mi = 0; mi < 2; ++mi) {
            int rowBase = m0 + wave * 32 + mi * 16 + quad * 4;
#pragma unroll
            for (int r = 0; r < 4; ++r) {
                out[(size_t)(rowBase + r) * NCLS + col] = acc[mi][ni][r] + bv;
            }
        }
    }
}

// ============================ Mask path ============================
__device__ inline float bilin14(const float* m14, float Y, float X, float eH, float eW) {
    float sy = fmaxf((Y + 0.5f) * 14.0f / eH - 0.5f, 0.0f);
    float sx = fmaxf((X + 0.5f) * 14.0f / eW - 0.5f, 0.0f);
    float r0f = floorf(sy);
    float c0f = floorf(sx);
    int r0 = (int)r0f;
    int r1 = min(r0 + 1, 13);
    int c0 = (int)c0f;
    int c1 = min(c0 + 1, 13);
    float fy = sy - r0f;
    float fx = sx - c0f;
    float g00 = m14[r0 * 14 + c0];
    float g01 = m14[r0 * 14 + c1];
    float g10 = m14[r1 * 14 + c0];
    float g11 = m14[r1 * 14 + c1];
    return g00 * (1.f - fy) * (1.f - fx) + g01 * (1.f - fy) * fx +
           g10 * fy * (1.f - fx) + g11 * fy * fx;
}

// One wave per (sample, box) pair. Threads 0..48 each own one 7x7 pooled cell
// (= 2x2 block of the 14x14 cm grid), then rank across 49 for top-25.
__global__ __launch_bounds__(64) void mask_kernel(const float* __restrict__ attn,
                                                  const int* __restrict__ pos,
                                                  float* __restrict__ out_mask) {
    const int p = blockIdx.x;      // 0..16383 ; row in concatenated mask
    const int b = p & (BSAMP - 1);
    const int o = p >> 13;         // 0: pos[:,0], 1: pos[:,1]
    const int t = threadIdx.x;

    __shared__ float m14[196];
    __shared__ float a7[49];

    for (int i = t; i < 196; i += 64) m14[i] = attn[(size_t)b * 196 + i];

    const int* pb = pos + (size_t)b * 12;
    const float top  = (float)(pb[o * 4 + 0] - pb[8]);
    const float left = (float)(pb[o * 4 + 1] - pb[9]);
    const float oH   = (float)pb[o * 4 + 2];
    const float oW   = (float)pb[o * 4 + 3];
    const float eH   = (float)pb[10];
    const float eW   = (float)pb[11];
    __syncthreads();

    int i7 = t / 7, j7 = t % 7;
    if (t < 49) {
        float s = 0.f;
#pragma unroll
        for (int dy = 0; dy < 2; ++dy) {
            int oy = 2 * i7 + dy;
            float ty = fmaxf((oy + 0.5f) * oH / 14.0f - 0.5f, 0.0f);
            float y0 = floorf(ty);
            float y1 = fminf(y0 + 1.0f, oH - 1.0f);
            float wy = ty - y0;
            float Y0 = top + y0, Y1 = top + y1;
#pragma unroll
            for (int dx = 0; dx < 2; ++dx) {
                int ox = 2 * j7 + dx;
                float tx = fmaxf((ox + 0.5f) * oW / 14.0f - 0.5f, 0.0f);
                float x0 = floorf(tx);
                float x1 = fminf(x0 + 1.0f, oW - 1.0f);
                float wx = tx - x0;
                float X0 = left + x0, X1 = left + x1;
                float v00 = bilin14(m14, Y0, X0, eH, eW);
                float v01 = bilin14(m14, Y0, X1, eH, eW);
                float v10 = bilin14(m14, Y1, X0, eH, eW);
                float v11 = bilin14(m14, Y1, X1, eH, eW);
                float cm = v00 * (1.f - wy) * (1.f - wx) + v01 * (1.f - wy) * wx +
                           v10 * wy * (1.f - wx) + v11 * wy * wx;
                s += cm;
            }
        }
        a7[t] = s * 0.25f;
    }
    __syncthreads();

    if (t < 49) {
        float mine = a7[t];
        int cnt = 0;
#pragma unroll 7
        for (int s2 = 0; s2 < 49; ++s2) {
            float v = a7[s2];
            cnt += (v > mine) || (v == mine && s2 < t);  // stable top_k tie-break
        }
        // kept (top-25) -> mask False (0.0); others True (1.0)
        float mv = (cnt < 25) ? 0.0f : 1.0f;
        float* base = out_mask + (size_t)p * 196;
        base[(2 * i7 + 0) * 14 + (2 * j7 + 0)] = mv;
        base[(2 * i7 + 0) * 14 + (2 * j7 + 1)] = mv;
        base[(2 * i7 + 1) * 14 + (2 * j7 + 0)] = mv;
        base[(2 * i7 + 1) * 14 + (2 * j7 + 1)] = mv;
    }
}

extern "C" void kernel_launch(void* const* d_in, const int* in_sizes, int n_in,
                              void* d_out, int out_size, void* d_ws, size_t ws_size,
                              hipStream_t stream) {
    const float* attn = (const float*)d_in[0];
    const int*   pos  = (const int*)d_in[1];
    const float* E    = (const float*)d_in[2];
    const float* W    = (const float*)d_in[3];
    const float* bias = (const float*)d_in[4];
    float* out = (float*)d_out;

    dim3 gridG(5, 128);  // n fastest -> 5 blocks sharing an E m-tile are adjacent (L3 reuse)
    gemm_kernel<<<gridG, 256, 0, stream>>>(E, W, bias, out);
    mask_kernel<<<16384, 64, 0, stream>>>(attn, pos, out + LOGITS_SIZE);
}